// Round 14
// baseline (9551.989 us; speedup 1.0000x reference)
//
#include <hip/hip_runtime.h>
#include <math.h>

#define TT_ 128
#define DD 64
#define HH 256
#define BB 16      // batch rows per block (MFMA M-tile)
#define NBLK 64    // 1024/16
#define NTHR 1024  // 16 waves, 1 N-tile (16 cols) per wave

// f32 LDS stride (elements): 260*4B = 1040B (odd multiple of 16B)
#define SA 260
// bf16 plane strides (elements): 264*2B = 528B, 72*2B = 144B (odd multiples of 16B)
#define SB 264
#define SXB 72

typedef short bf16x8 __attribute__((ext_vector_type(8)));
typedef float f32x4 __attribute__((ext_vector_type(4)));
typedef unsigned int uint;
typedef unsigned short ushort;

// ---- fragment-linear packed weights (bf16 hi/lo pairs), written by prep ----
// frag elem (tile t, oct o): W[t*16 + l%16][o*32 + (l/16)*8 + j], hi at +0, lo at +512
__device__ ushort g_W1p[16 * 8 * 2 * 512];    // W1  (256x256): t*8192 + o*1024
__device__ ushort g_W2p[16 * 8 * 2 * 512];    // W2  (256x256)
__device__ ushort g_Wrzp[32 * 10 * 2 * 512];  // Whh rows 0..511 (o<8) | Wih rows 0..511 (o=8,9): t*10240 + o*1024
__device__ ushort g_Whnp[16 * 8 * 2 * 512];   // Whh rows 512..767
__device__ ushort g_Winp[16 * 2 * 512];       // Wih rows 512..767 (hi only): t*1024 + o*512

__device__ __forceinline__ ushort bf16_rne(float f) {
  uint u = __builtin_bit_cast(uint, f);
  return (ushort)((u + 0x7fffu + ((u >> 16) & 1u)) >> 16);
}
__device__ __forceinline__ float bf16_f32(ushort h) {
  uint u = ((uint)h) << 16;
  return __builtin_bit_cast(float, u);
}
// truncation split: hi+lo reproduces f to ~2^-17 rel
__device__ __forceinline__ void hl_split(float f, ushort& hi, ushort& lo) {
  const uint u = __builtin_bit_cast(uint, f);
  hi = (ushort)(u >> 16);
  const float fh = __builtin_bit_cast(float, u & 0xffff0000u);
  lo = (ushort)(__builtin_bit_cast(uint, f - fh) >> 16);
}

__global__ __launch_bounds__(256) void prep(
    const float* __restrict__ W1, const float* __restrict__ W2,
    const float* __restrict__ Wih, const float* __restrict__ Whh)
{
  const int s = blockIdx.x * 256 + threadIdx.x;
  const int S1 = 16 * 8 * 512;
  const int S2 = S1 + 16 * 8 * 512;
  const int S3 = S2 + 32 * 10 * 512;
  const int S4 = S3 + 16 * 8 * 512;
  const int S5 = S4 + 16 * 2 * 512;
  if (s >= S5) return;

  if (s < S2) {  // W1 / W2
    const int r = (s < S1) ? s : s - S1;
    const int t = r / (8 * 512);
    const int o = (r / 512) & 7;
    const int pos = r & 511;
    const int l = pos >> 3, j = pos & 7;
    const int n = t * 16 + (l & 15);
    const int k = o * 32 + (l >> 4) * 8 + j;
    const float w = (s < S1) ? W1[n * HH + k] : W2[n * HH + k];
    ushort hi = bf16_rne(w);
    ushort lo = bf16_rne(w - bf16_f32(hi));
    ushort* dst = (s < S1) ? g_W1p : g_W2p;
    dst[((t * 8 + o) * 2) * 512 + pos] = hi;
    dst[((t * 8 + o) * 2 + 1) * 512 + pos] = lo;
  } else if (s < S3) {  // Wrz
    const int r = s - S2;
    const int t = r / (10 * 512);
    const int o = (r / 512) % 10;
    const int pos = r & 511;
    const int l = pos >> 3, j = pos & 7;
    const int n = t * 16 + (l & 15);
    float w;
    if (o < 8) w = Whh[n * HH + o * 32 + (l >> 4) * 8 + j];
    else       w = Wih[n * DD + (o - 8) * 32 + (l >> 4) * 8 + j];
    ushort hi = bf16_rne(w);
    ushort lo = bf16_rne(w - bf16_f32(hi));
    g_Wrzp[((t * 10 + o) * 2) * 512 + pos] = hi;
    g_Wrzp[((t * 10 + o) * 2 + 1) * 512 + pos] = lo;
  } else if (s < S4) {  // Whn
    const int r = s - S3;
    const int t = r / (8 * 512);
    const int o = (r / 512) & 7;
    const int pos = r & 511;
    const int l = pos >> 3, j = pos & 7;
    const int n = 512 + t * 16 + (l & 15);
    const float w = Whh[n * HH + o * 32 + (l >> 4) * 8 + j];
    ushort hi = bf16_rne(w);
    ushort lo = bf16_rne(w - bf16_f32(hi));
    g_Whnp[((t * 8 + o) * 2) * 512 + pos] = hi;
    g_Whnp[((t * 8 + o) * 2 + 1) * 512 + pos] = lo;
  } else {  // Win (hi only)
    const int r = s - S4;
    const int t = r / (2 * 512);
    const int o = (r / 512) & 1;
    const int pos = r & 511;
    const int l = pos >> 3, j = pos & 7;
    const int n = 512 + t * 16 + (l & 15);
    const float w = Wih[n * DD + o * 32 + (l >> 4) * 8 + j];
    g_Winp[(t * 2 + o) * 512 + pos] = bf16_rne(w);
  }
}

#define MFMA(A, B, C) __builtin_amdgcn_mfma_f32_16x16x32_bf16((A), (B), (C), 0, 0, 0)

// LDS-only barrier: waits lgkm only. Does NOT drain vmcnt, so the
// global_load_lds prefetch queue survives barriers.
#define LBAR() asm volatile("s_waitcnt lgkmcnt(0)\ns_barrier" ::: "memory")

// Cache-warming prefetch: async global->LDS DMA into a dummy slot.
// Zero VGPRs consumed (sidesteps the 64-reg budget that killed register
// prefetch in R8-R11); the line lands in L1/L2 en route.
__device__ __forceinline__ void pfq(const ushort* g, ushort* lds) {
  __builtin_amdgcn_global_load_lds(
      (const __attribute__((address_space(1))) void*)g,
      (__attribute__((address_space(3))) void*)lds,
      16, 0, 0);
}
__device__ __forceinline__ void pf_t16(const ushort* base, ushort* d) {
#pragma unroll
  for (int o = 0; o < 8; ++o) {
    pfq(base + o * 1024, d);
    pfq(base + o * 1024 + 512, d);
  }
}

// 1 N-tile, K=256, 3-term split accumulation (weights cache-warm from the
// step-top prefetch burst; depth-2 consume is then cheap).
__device__ __forceinline__ f32x4 mm1(const ushort* __restrict__ Ahi,
                                     const ushort* __restrict__ Alo,
                                     const ushort* __restrict__ pack,
                                     int tile, int lane, int aoff, f32x4 acc)
{
  const ushort* wp = pack + (size_t)tile * 8192 + lane * 8;
  f32x4 a0 = acc;
  f32x4 a1 = {0.f, 0.f, 0.f, 0.f};
#pragma unroll
  for (int o = 0; o < 8; ++o) {
    const bf16x8 wh = *(const bf16x8*)(wp + o * 1024);
    const bf16x8 wl = *(const bf16x8*)(wp + o * 1024 + 512);
    const bf16x8 ah = *(const bf16x8*)(Ahi + aoff + o * 32);
    const bf16x8 al = *(const bf16x8*)(Alo + aoff + o * 32);
    f32x4& ac = (o & 1) ? a1 : a0;
    ac = MFMA(ah, wh, ac);
    ac = MFMA(al, wh, ac);
    ac = MFMA(ah, wl, ac);
  }
  return a0 + a1;
}

__global__ __launch_bounds__(NTHR) void odegru_kernel(
    const float* __restrict__ x, const float* __restrict__ times,
    const float* __restrict__ mask,
    const float* __restrict__ b1, const float* __restrict__ b2,
    const float* __restrict__ bih, const float* __restrict__ bhh,
    float* __restrict__ out)
{
  // f32 state
  __shared__ __align__(16) float sAh[BB * SA];    // h (full f32 state)
  __shared__ __align__(16) float sAin[BB * SA];   // h_ode / RK stage input (f32)
  // bf16 hi/lo matmul planes
  __shared__ __align__(16) ushort sAhh[BB * SB], sAhl[BB * SB];
  __shared__ __align__(16) ushort sAinh[BB * SB], sAinl[BB * SB];
  __shared__ __align__(16) ushort sUh[BB * SB], sUl[BB * SB];
  __shared__ __align__(16) ushort sXh[BB * SXB], sXl[BB * SXB];
  __shared__ __align__(16) float sMt[TT_ * BB];   // mask transposed [t][b]
  __shared__ __align__(16) ushort sDummy[512];    // prefetch sink (never read)

  const int tid = threadIdx.x;
  const int lane = tid & 63;
  const int wv = tid >> 6;     // wave 0..15, owns output col-tile wv
  const int l15 = lane & 15;
  const int lq = lane >> 4;    // 0..3
  const int b0 = blockIdx.x * BB;
  const int aoff = l15 * SB + lq * 8;
  const int xoff = l15 * SXB + lq * 8;

  const int c = wv * 16 + l15;       // this thread's output column
  const float b1c = b1[c];
  const float b2c = b2[c];
  const float brz_r = bih[c] + bhh[c];
  const float brz_z = bih[c + 256] + bhh[c + 256];
  const float bn_i = bih[c + 512];
  const float bn_h = bhh[c + 512];

  const f32x4 Z = {0.f, 0.f, 0.f, 0.f};

  // per-wave weight base pointers (lane-spread)
  const ushort* W1b = g_W1p + (size_t)wv * 8192 + lane * 8;
  const ushort* W2b = g_W2p + (size_t)wv * 8192 + lane * 8;
  const ushort* Wrb = g_Wrzp + (size_t)wv * 10240 + lane * 8;
  const ushort* Wzb = g_Wrzp + (size_t)(16 + wv) * 10240 + lane * 8;
  const ushort* Whb = g_Whnp + (size_t)wv * 8192 + lane * 8;
  const ushort* Wib = g_Winp + (size_t)wv * 1024 + lane * 8;

  // stage mask transposed: sMt[t][b]
  {
    const int e0 = tid, e1 = tid + 1024;
    sMt[(e0 & 127) * BB + (e0 >> 7)] = mask[(size_t)(b0 + (e0 >> 7)) * TT_ + (e0 & 127)];
    sMt[(e1 & 127) * BB + (e1 >> 7)] = mask[(size_t)(b0 + (e1 >> 7)) * TT_ + (e1 & 127)];
  }

  // feval: A-planes -> kv (per-thread: col c, batches lq*4+q)
  auto feval = [&](const ushort* Ahi, const ushort* Alo, f32x4& kv) {
    f32x4 a = mm1(Ahi, Alo, g_W1p, wv, lane, aoff, Z);
#pragma unroll
    for (int q = 0; q < 4; ++q) {
      const int b = lq * 4 + q;
      const float u = fmaxf(a[q] + b1c, 0.f);
      ushort hi, lo; hl_split(u, hi, lo);
      sUh[b * SB + c] = hi;
      sUl[b * SB + c] = lo;
    }
    LBAR();
    f32x4 p = mm1(sUh, sUl, g_W2p, wv, lane, aoff, Z);
    kv = p + b2c;
  };

  // sAin <- sAh + coef*v (f32) and refresh Ain planes
  auto wAin = [&](float coef, const f32x4& v) {
#pragma unroll
    for (int q = 0; q < 4; ++q) {
      const int b = lq * 4 + q;
      const float nv = sAh[b * SA + c] + coef * v[q];
      sAin[b * SA + c] = nv;
      ushort hi, lo; hl_split(nv, hi, lo);
      sAinh[b * SB + c] = hi;
      sAinl[b * SB + c] = lo;
    }
  };

  for (int t = 0; t < TT_; ++t) {
    // stage x[:, t, :] as hi/lo planes
    {
      const int b = tid >> 6, d = tid & 63;
      const float v = x[((size_t)(b0 + b) * TT_ + t) * DD + d];
      ushort hi, lo; hl_split(v, hi, lo);
      sXh[b * SXB + d] = hi;
      sXl[b * SXB + d] = lo;
    }
    // ---- prefetch burst: this step's full per-wave weight set (~90 KB).
    // LBAR below does NOT drain vmcnt; k1's first weight wait streams it once.
    pf_t16(W1b, sDummy);
    pf_t16(W2b, sDummy);
    pf_t16(Wrb, sDummy); pfq(Wrb + 8 * 1024, sDummy); pfq(Wrb + 9 * 1024, sDummy);
    pf_t16(Wzb, sDummy); pfq(Wzb + 8 * 1024, sDummy); pfq(Wzb + 9 * 1024, sDummy);
    pf_t16(Whb, sDummy);
    pfq(Wib, sDummy); pfq(Wib + 512, sDummy);

    if (t == 0) {
      const int cc = tid & 255;
#pragma unroll
      for (int q = 0; q < 4; ++q) {
        const int b = (tid >> 8) * 4 + q;
        sAin[b * SA + cc] = 0.f;
        sAinh[b * SB + cc] = 0;
        sAinl[b * SB + cc] = 0;
      }
    }
    LBAR();

    if (t > 0) {
      const float dtv = times[t] - times[t - 1];
      f32x4 kv, ks;
      // k1 (reads h planes)
      feval(sAhh, sAhl, kv);
      ks = kv;
      wAin(0.5f * dtv, kv);
      LBAR();
      // k2
      feval(sAinh, sAinl, kv);
      ks += 2.0f * kv;
      wAin(0.5f * dtv, kv);
      LBAR();
      // k3
      feval(sAinh, sAinl, kv);
      ks += 2.0f * kv;
      wAin(dtv, kv);
      LBAR();
      // k4
      feval(sAinh, sAinl, kv);
      ks += kv;
      wAin(dtv * (1.0f / 6.0f), ks);  // sAin <- h_ode
      LBAR();
    }

    // ---- GRU: fused r/z/hn oct-loop sharing A-fragments (1/3 the A-plane
    // LDS reads of the unfused form), then the K=64 x-parts ----
    {
      f32x4 r0 = Z, r1 = Z, z0 = Z, z1 = Z, h0 = Z, h1 = Z;
#pragma unroll
      for (int o = 0; o < 8; ++o) {
        const int ac = aoff + o * 32;
        const bf16x8 ah = *(const bf16x8*)(sAinh + ac);
        const bf16x8 al = *(const bf16x8*)(sAinl + ac);
        const bf16x8 wrh = *(const bf16x8*)(Wrb + o * 1024);
        const bf16x8 wrl = *(const bf16x8*)(Wrb + o * 1024 + 512);
        const bf16x8 wzh = *(const bf16x8*)(Wzb + o * 1024);
        const bf16x8 wzl = *(const bf16x8*)(Wzb + o * 1024 + 512);
        const bf16x8 whh = *(const bf16x8*)(Whb + o * 1024);
        const bf16x8 whl = *(const bf16x8*)(Whb + o * 1024 + 512);
        r0 = MFMA(ah, wrh, r0); r1 = MFMA(al, wrh, r1); r0 = MFMA(ah, wrl, r0);
        z0 = MFMA(ah, wzh, z0); z1 = MFMA(al, wzh, z1); z0 = MFMA(ah, wzl, z0);
        h0 = MFMA(ah, whh, h0); h1 = MFMA(al, whh, h1); h0 = MFMA(ah, whl, h0);
      }
      f32x4 ar = r0 + r1, az = z0 + z1, ahn = h0 + h1;
      f32x4 ain = Z;
#pragma unroll
      for (int o = 0; o < 2; ++o) {
        const int xc = xoff + o * 32;
        const bf16x8 xh = *(const bf16x8*)(sXh + xc);
        const bf16x8 xl = *(const bf16x8*)(sXl + xc);
        const bf16x8 wr = *(const bf16x8*)(Wrb + (8 + o) * 1024);
        const bf16x8 wz = *(const bf16x8*)(Wzb + (8 + o) * 1024);
        const bf16x8 wi = *(const bf16x8*)(Wib + o * 512);
        ar = MFMA(xh, wr, ar); ar = MFMA(xl, wr, ar);
        az = MFMA(xh, wz, az); az = MFMA(xl, wz, az);
        ain = MFMA(xh, wi, ain); ain = MFMA(xl, wi, ain);
      }

#pragma unroll
      for (int q = 0; q < 4; ++q) {
        const int b = lq * 4 + q;
        const float gr = ar[q] + brz_r;
        const float gz = az[q] + brz_z;
        const float hn = ahn[q] + bn_h;
        const float gn = ain[q] + bn_i;
        const float hode = sAin[b * SA + c];
        const float rg = 1.f / (1.f + __expf(-gr));
        const float zg = 1.f / (1.f + __expf(-gz));
        const float ng = 1.f - 2.f / (__expf(2.f * (gn + rg * hn)) + 1.f);
        const float hnext = (1.f - zg) * ng + zg * hode;
        const float m = sMt[t * BB + b];
        const float hnew = m * hnext + (1.f - m) * hode;
        out[((size_t)(b0 + b) * TT_ + t) * HH + c] = hnew;
        sAh[b * SA + c] = hnew;
        ushort hi, lo; hl_split(hnew, hi, lo);
        sAhh[b * SB + c] = hi;
        sAhl[b * SB + c] = lo;
      }
    }
    LBAR();
  }
}

extern "C" void kernel_launch(void* const* d_in, const int* in_sizes, int n_in,
                              void* d_out, int out_size, void* d_ws, size_t ws_size,
                              hipStream_t stream) {
  (void)in_sizes; (void)n_in; (void)d_ws; (void)ws_size; (void)out_size;
  const float* x     = (const float*)d_in[0];
  const float* times = (const float*)d_in[1];
  const float* mask  = (const float*)d_in[2];
  const float* W1    = (const float*)d_in[3];
  const float* b1    = (const float*)d_in[4];
  const float* W2    = (const float*)d_in[5];
  const float* b2    = (const float*)d_in[6];
  const float* Wih   = (const float*)d_in[7];
  const float* bih   = (const float*)d_in[8];
  const float* Whh   = (const float*)d_in[9];
  const float* bhh   = (const float*)d_in[10];
  float* out = (float*)d_out;

  hipLaunchKernelGGL(prep, dim3((376832 + 255) / 256), dim3(256), 0, stream,
                     W1, W2, Wih, Whh);
  hipLaunchKernelGGL(odegru_kernel, dim3(NBLK), dim3(NTHR), 0, stream,
                     x, times, mask, b1, b2, bih, bhh, out);
}